// Round 1
// baseline (442.003 us; speedup 1.0000x reference)
//
#include <hip/hip_runtime.h>

#define BB 16384
#define KK 64
#define DD 128
#define SPLIT 4

// ---------------------------------------------------------------------------
// K1: one wave per row, one lane per cluster.
// Computes dist_sq, log_resp (with log(clip(softmax,1e-8))), argmin assign,
// and accumulates cluster_weight + per-cluster x sums via global atomics.
// ---------------------------------------------------------------------------
__global__ __launch_bounds__(256) void k_rows(
    const float* __restrict__ x, const float* __restrict__ centers,
    float* __restrict__ log_resp, int* __restrict__ assign,
    float* __restrict__ cw, float* __restrict__ emp_total)
{
    __shared__ float c_t[DD * 65];   // transposed + padded: c_t[d*65 + k]
    __shared__ float x_s[4][DD];

    const int tid = threadIdx.x;

    // coalesced global read, transposed LDS write (pad 65 breaks conflicts)
    for (int i = tid; i < KK * DD; i += 256) {
        int k = i >> 7, d = i & 127;
        c_t[d * 65 + k] = centers[i];
    }
    __syncthreads();

    const int wave = tid >> 6;
    const int lane = tid & 63;
    const int wglobal = blockIdx.x * 4 + wave;
    const int nwaves = gridDim.x * 4;   // grid fixed at 1024 -> 4096 waves, 4 rows each

    for (int row = wglobal; row < BB; row += nwaves) {
        float2 v = ((const float2*)(x + (size_t)row * DD))[lane];
        x_s[wave][2 * lane]     = v.x;
        x_s[wave][2 * lane + 1] = v.y;
        __syncthreads();   // uniform trip count across all 4 waves

        float dist = 0.f;
        #pragma unroll
        for (int d = 0; d < DD; ++d) {
            float diff = x_s[wave][d] - c_t[d * 65 + lane];
            dist = fmaf(diff, diff, dist);
        }
        __syncthreads();

        // butterfly argmin all-reduce, tie -> lowest index (matches jnp.argmin)
        float mval = dist; int midx = lane;
        #pragma unroll
        for (int off = 32; off > 0; off >>= 1) {
            float ov = __shfl_xor(mval, off);
            int   oi = __shfl_xor(midx, off);
            if (ov < mval || (ov == mval && oi < midx)) { mval = ov; midx = oi; }
        }

        // log-softmax with clip floor: log(1e-8f) = -18.4206807
        float e = -0.5f * dist;
        float m = -0.5f * mval;          // max over lanes of expo (exact: *0.5 is exact)
        float p = expf(e - m);
        float s = p;
        #pragma unroll
        for (int off = 32; off > 0; off >>= 1) s += __shfl_xor(s, off);
        float lr = e - m - logf(s);
        lr = fmaxf(lr, -18.4206807f);
        log_resp[(size_t)row * KK + lane] = lr;

        if (lane == 0) {
            assign[row] = midx;
            atomicAdd(&cw[midx], 1.0f);
        }
        atomicAdd(&emp_total[midx * DD + 2 * lane],     v.x);
        atomicAdd(&emp_total[midx * DD + 2 * lane + 1], v.y);
    }
}

// ---------------------------------------------------------------------------
// K2: mu = emp_total / (cw + 1e-7)
// ---------------------------------------------------------------------------
__global__ __launch_bounds__(256) void k_mean(
    const float* __restrict__ emp_total, const float* __restrict__ cw,
    float* __restrict__ mu)
{
    int i = blockIdx.x * 256 + threadIdx.x;   // 8192 total
    mu[i] = emp_total[i] / (cw[i >> 7] + 1e-7f);
}

// ---------------------------------------------------------------------------
// K3: per (cluster, row-range-split) block: compact member list in LDS, then
// register-tiled accumulation of sum_{members} (x-mu)(x-mu)^T.
// Thread t owns an 8x8 tile: rows (t>>4)*8.., cols (t&15)*8..
// Partial C merged into global covar buffer with atomics.
// ---------------------------------------------------------------------------
__global__ __launch_bounds__(256) void k_covar(
    const float* __restrict__ x, const int* __restrict__ assign,
    const float* __restrict__ mu, float* __restrict__ covar)
{
    __shared__ int   mlist[BB / SPLIT];   // 4096 ints
    __shared__ float mu_s[DD];
    __shared__ float xr_s[4][DD];
    __shared__ int   mcount;

    const int tid = threadIdx.x;
    const int k = blockIdx.x >> 2;
    const int s = blockIdx.x & 3;
    const int chunk = BB / SPLIT;         // 4096
    const int base = s * chunk;

    if (tid == 0) mcount = 0;
    if (tid < DD) mu_s[tid] = mu[k * DD + tid];
    __syncthreads();

    for (int j = 0; j < chunk / 256; ++j) {   // 16 coalesced sweeps
        int r = base + j * 256 + tid;
        if (assign[r] == k) {
            int p = atomicAdd(&mcount, 1);
            mlist[p] = r;
        }
    }
    __syncthreads();
    const int cnt = mcount;

    const int tr = tid >> 4;      // 0..15
    const int tc = tid & 15;      // 0..15
    float acc[8][8];
    #pragma unroll
    for (int i = 0; i < 8; ++i)
        #pragma unroll
        for (int l = 0; l < 8; ++l) acc[i][l] = 0.f;

    const int jrow = tid >> 6;            // which of 4 staged rows this thread loads
    const int dd   = (tid & 63) * 2;      // which float2 of that row

    for (int it = 0; it < cnt; it += 4) {
        __syncthreads();   // WAR: previous iteration's reads done before overwrite
        int mi = it + jrow;
        float2 val = {0.f, 0.f};          // padding rows contribute 0 to acc
        if (mi < cnt) {
            int r = mlist[mi];
            float2 xv = ((const float2*)(x + (size_t)r * DD))[tid & 63];
            val.x = xv.x - mu_s[dd];
            val.y = xv.y - mu_s[dd + 1];
        }
        xr_s[jrow][dd]     = val.x;
        xr_s[jrow][dd + 1] = val.y;
        __syncthreads();   // RAW

        #pragma unroll
        for (int j = 0; j < 4; ++j) {
            float4 a0 = *(const float4*)&xr_s[j][tr * 8];
            float4 a1 = *(const float4*)&xr_s[j][tr * 8 + 4];
            float4 b0 = *(const float4*)&xr_s[j][tc * 8];
            float4 b1 = *(const float4*)&xr_s[j][tc * 8 + 4];
            float av[8] = {a0.x, a0.y, a0.z, a0.w, a1.x, a1.y, a1.z, a1.w};
            float bv[8] = {b0.x, b0.y, b0.z, b0.w, b1.x, b1.y, b1.z, b1.w};
            #pragma unroll
            for (int i = 0; i < 8; ++i)
                #pragma unroll
                for (int l = 0; l < 8; ++l)
                    acc[i][l] = fmaf(av[i], bv[l], acc[i][l]);
        }
    }

    float* cbase = covar + (size_t)k * DD * DD;
    #pragma unroll
    for (int i = 0; i < 8; ++i)
        #pragma unroll
        for (int l = 0; l < 8; ++l)
            atomicAdd(&cbase[(tr * 8 + i) * DD + tc * 8 + l], acc[i][l]);
}

// ---------------------------------------------------------------------------
// K4: per-cluster block: reduce covar -> diag/off squared errors, mean MSE,
// atomicAdd the two scalar outputs.
// ---------------------------------------------------------------------------
__global__ __launch_bounds__(256) void k_final(
    const float* __restrict__ covar, const float* __restrict__ cw,
    const float* __restrict__ mu, const float* __restrict__ centers,
    float* __restrict__ outscalars)
{
    const int k = blockIdx.x;
    const int tid = threadIdx.x;
    const float w = cw[k];
    const float inv = 1.0f / (w + 1e-7f);

    float ds = 0.f, os = 0.f, mm = 0.f;
    const float* cb = covar + (size_t)k * DD * DD;
    for (int i = tid; i < DD * DD; i += 256) {
        float v = cb[i] * inv;
        int d = i >> 7, e = i & 127;
        if (d == e) { float t = v - 1.f; ds += t * t; }
        else        { os += v * v; }
    }
    if (tid < DD) {
        float t = mu[k * DD + tid] - centers[k * DD + tid];
        mm = t * t;
    }

    #pragma unroll
    for (int off = 32; off > 0; off >>= 1) {
        ds += __shfl_down(ds, off);
        os += __shfl_down(os, off);
        mm += __shfl_down(mm, off);
    }
    __shared__ float rds[4], ros[4], rmm[4];
    int wv = tid >> 6, ln = tid & 63;
    if (ln == 0) { rds[wv] = ds; ros[wv] = os; rmm[wv] = mm; }
    __syncthreads();
    if (tid == 0) {
        float DS = rds[0] + rds[1] + rds[2] + rds[3];
        float OS = ros[0] + ros[1] + ros[2] + ros[3];
        float MM = rmm[0] + rmm[1] + rmm[2] + rmm[3];
        const float bd = (float)BB * (float)DD;            // 2097152
        float meanc = w * MM / bd;
        float covc  = w * DS / bd + w * OS / (bd * (float)(DD - 1));
        atomicAdd(&outscalars[0], meanc);
        atomicAdd(&outscalars[1], covc);
    }
}

// ---------------------------------------------------------------------------
extern "C" void kernel_launch(void* const* d_in, const int* in_sizes, int n_in,
                              void* d_out, int out_size, void* d_ws, size_t ws_size,
                              hipStream_t stream) {
    const float* x = (const float*)d_in[0];
    const float* centers = (const float*)d_in[1];
    float* out = (float*)d_out;

    char* ws = (char*)d_ws;
    float* cw        = (float*)ws;                                  //    64 f
    float* emp_total = (float*)(ws + 256);                          //  8192 f
    float* covar     = (float*)(ws + 256 + 32768);                  // 64*16384 f = 4 MB
    float* mu        = (float*)(ws + 256 + 32768 + 4194304);        //  8192 f
    int*   assign    = (int*)  (ws + 256 + 32768 + 4194304 + 32768);// 16384 i

    // zero the atomically-accumulated buffers (cw + emp_total + covar)
    hipMemsetAsync(d_ws, 0, 256 + 32768 + 4194304, stream);
    // zero the two scalar outputs (accumulated via atomics)
    hipMemsetAsync(out + (size_t)BB * KK, 0, 2 * sizeof(float), stream);

    k_rows <<<1024, 256, 0, stream>>>(x, centers, out, assign, cw, emp_total);
    k_mean <<<32,   256, 0, stream>>>(emp_total, cw, mu);
    k_covar<<<KK * SPLIT, 256, 0, stream>>>(x, assign, mu, covar);
    k_final<<<KK,   256, 0, stream>>>(covar, cw, mu, centers, out + (size_t)BB * KK);
}

// Round 2
// 193.837 us; speedup vs baseline: 2.2803x; 2.2803x over previous
//
#include <hip/hip_runtime.h>

#define BB 16384
#define KK 64
#define DD 128
#define SEG 256          // rows per covariance work-item
#define MAXITEMS 128     // sum_k ceil(cnt_k/SEG) <= BB/SEG + KK = 64+64

// ---------------------------------------------------------------------------
// K1: one wave per row, one lane per cluster. log_resp + argmin assign only.
// (No atomics: R1 showed 2.1M same-address emp_total atomics cost ~190us.)
// ---------------------------------------------------------------------------
__global__ __launch_bounds__(256) void k_rows(
    const float* __restrict__ x, const float* __restrict__ centers,
    float* __restrict__ log_resp, int* __restrict__ assign)
{
    __shared__ float c_t[DD * 65];   // transposed + padded: c_t[d*65 + k]
    __shared__ float x_s[4][DD];

    const int tid = threadIdx.x;

    for (int i = tid; i < KK * DD; i += 256) {
        int k = i >> 7, d = i & 127;
        c_t[d * 65 + k] = centers[i];
    }
    __syncthreads();

    const int wave = tid >> 6;
    const int lane = tid & 63;
    const int wglobal = blockIdx.x * 4 + wave;
    const int nwaves = gridDim.x * 4;   // 4096 waves, 4 rows each (uniform)

    for (int row = wglobal; row < BB; row += nwaves) {
        float2 v = ((const float2*)(x + (size_t)row * DD))[lane];
        x_s[wave][2 * lane]     = v.x;
        x_s[wave][2 * lane + 1] = v.y;
        __syncthreads();

        float dist = 0.f;
        #pragma unroll
        for (int d = 0; d < DD; ++d) {
            float diff = x_s[wave][d] - c_t[d * 65 + lane];
            dist = fmaf(diff, diff, dist);
        }
        __syncthreads();

        // butterfly argmin, tie -> lowest index (matches jnp.argmin)
        float mval = dist; int midx = lane;
        #pragma unroll
        for (int off = 32; off > 0; off >>= 1) {
            float ov = __shfl_xor(mval, off);
            int   oi = __shfl_xor(midx, off);
            if (ov < mval || (ov == mval && oi < midx)) { mval = ov; midx = oi; }
        }

        float e = -0.5f * dist;
        float m = -0.5f * mval;
        float p = expf(e - m);
        float s = p;
        #pragma unroll
        for (int off = 32; off > 0; off >>= 1) s += __shfl_xor(s, off);
        float lr = e - m - logf(s);
        lr = fmaxf(lr, -18.4206807f);    // log(1e-8)
        log_resp[(size_t)row * KK + lane] = lr;

        if (lane == 0) assign[row] = midx;
    }
}

// ---------------------------------------------------------------------------
// K2 (1 block, 1024 threads): counting sort of rows by cluster + work items.
// Per-wave privatized histogram -> cross-wave prefix -> scatter.
// ---------------------------------------------------------------------------
__global__ __launch_bounds__(1024) void k_sort(
    const int* __restrict__ assign, int* __restrict__ sorted,
    float* __restrict__ cw, int4* __restrict__ items, int* __restrict__ item_count)
{
    __shared__ int whist[16][64];   // per-wave histogram / exclusive prefix
    __shared__ int wcur[16][64];    // per-wave scatter cursors
    __shared__ int cnt_s[64];
    __shared__ int cbase_s[64];

    const int tid = threadIdx.x;
    const int w = tid >> 6;
    const int lane = tid & 63;

    whist[w][lane] = 0;
    __syncthreads();

    // each wave handles rows [w*1024, (w+1)*1024)
    #pragma unroll
    for (int i = 0; i < 16; ++i) {
        int r = w * 1024 + i * 64 + lane;
        atomicAdd(&whist[w][assign[r]], 1);
    }
    __syncthreads();

    // per-cluster: totals + exclusive prefix across waves
    if (tid < 64) {
        int run = 0;
        #pragma unroll
        for (int ww = 0; ww < 16; ++ww) {
            int t = whist[ww][tid];
            whist[ww][tid] = run;
            run += t;
        }
        cnt_s[tid] = run;
        cw[tid] = (float)run;
    }
    __syncthreads();

    // serial (thread 0): cluster bases + segment work items
    if (tid == 0) {
        int base = 0;
        for (int k = 0; k < KK; ++k) { cbase_s[k] = base; base += cnt_s[k]; }
        int ic = 0;
        for (int k = 0; k < KK; ++k) {
            int c = cnt_s[k];
            for (int s = 0; s < c; s += SEG) {
                int4 it; it.x = k; it.y = cbase_s[k] + s;
                it.z = min(SEG, c - s); it.w = 0;
                items[ic++] = it;
            }
        }
        *item_count = ic;
    }
    __syncthreads();

    wcur[w][lane] = cbase_s[lane] + whist[w][lane];
    __syncthreads();

    #pragma unroll
    for (int i = 0; i < 16; ++i) {
        int r = w * 1024 + i * 64 + lane;
        int a = assign[r];
        int p = atomicAdd(&wcur[w][a], 1);
        sorted[p] = r;
    }
}

// ---------------------------------------------------------------------------
// K3: one block per segment (<=256 member rows of one cluster).
// Register-tiled 8x8 accumulation of Sxx = sum x x^T (no mean needed) and
// column sums. Merge via global f32 atomics (<=64-way contention).
// ---------------------------------------------------------------------------
__global__ __launch_bounds__(256) void k_seg(
    const float* __restrict__ x, const int* __restrict__ sorted,
    const int4* __restrict__ items, const int* __restrict__ item_count,
    float* __restrict__ Sxx, float* __restrict__ emp)
{
    if ((int)blockIdx.x >= *item_count) return;
    int4 it = items[blockIdx.x];
    const int k = it.x, gstart = it.y, len = it.z;

    __shared__ int rows_s[SEG];
    __shared__ float xr_s[8][DD];

    const int tid = threadIdx.x;
    if (tid < len) rows_s[tid] = sorted[gstart + tid];

    const int jrow = tid >> 5;        // 0..7 : staged row this thread loads
    const int dc   = (tid & 31) * 4;  // float4 column offset
    const int tr = tid >> 4, tc = tid & 15;

    float acc[8][8];
    #pragma unroll
    for (int i = 0; i < 8; ++i)
        #pragma unroll
        for (int l = 0; l < 8; ++l) acc[i][l] = 0.f;
    float cs0 = 0.f, cs1 = 0.f, cs2 = 0.f, cs3 = 0.f;

    __syncthreads();   // rows_s ready

    for (int it0 = 0; it0 < len; it0 += 8) {
        __syncthreads();   // WAR on xr_s
        float4 xv = {0.f, 0.f, 0.f, 0.f};
        int mi = it0 + jrow;
        if (mi < len)
            xv = *(const float4*)(x + (size_t)rows_s[mi] * DD + dc);
        *(float4*)&xr_s[jrow][dc] = xv;
        cs0 += xv.x; cs1 += xv.y; cs2 += xv.z; cs3 += xv.w;
        __syncthreads();   // RAW

        #pragma unroll
        for (int j = 0; j < 8; ++j) {
            float4 a0 = *(const float4*)&xr_s[j][tr * 8];
            float4 a1 = *(const float4*)&xr_s[j][tr * 8 + 4];
            float4 b0 = *(const float4*)&xr_s[j][tc * 8];
            float4 b1 = *(const float4*)&xr_s[j][tc * 8 + 4];
            float av[8] = {a0.x, a0.y, a0.z, a0.w, a1.x, a1.y, a1.z, a1.w};
            float bv[8] = {b0.x, b0.y, b0.z, b0.w, b1.x, b1.y, b1.z, b1.w};
            #pragma unroll
            for (int i = 0; i < 8; ++i)
                #pragma unroll
                for (int l = 0; l < 8; ++l)
                    acc[i][l] = fmaf(av[i], bv[l], acc[i][l]);
        }
    }

    float* sb = Sxx + (size_t)k * DD * DD;
    #pragma unroll
    for (int i = 0; i < 8; ++i)
        #pragma unroll
        for (int l = 0; l < 8; ++l)
            atomicAdd(&sb[(tr * 8 + i) * DD + tc * 8 + l], acc[i][l]);

    atomicAdd(&emp[k * DD + dc],     cs0);
    atomicAdd(&emp[k * DD + dc + 1], cs1);
    atomicAdd(&emp[k * DD + dc + 2], cs2);
    atomicAdd(&emp[k * DD + dc + 3], cs3);
}

// ---------------------------------------------------------------------------
// K4: per-cluster block: covar from Sxx/emp/cw (exact centered form),
// diag/off squared errors + mean MSE -> atomicAdd two scalar outputs.
// ---------------------------------------------------------------------------
__global__ __launch_bounds__(256) void k_final(
    const float* __restrict__ Sxx, const float* __restrict__ emp,
    const float* __restrict__ cw, const float* __restrict__ centers,
    float* __restrict__ outscalars)
{
    const int k = blockIdx.x;
    const int tid = threadIdx.x;
    const float w = cw[k];
    const float inv = 1.0f / (w + 1e-7f);

    __shared__ float mu_s[DD], emp_s[DD];
    if (tid < DD) {
        float e = emp[k * DD + tid];
        emp_s[tid] = e;
        mu_s[tid] = e * inv;
    }
    __syncthreads();

    float ds = 0.f, os = 0.f, mm = 0.f;
    const float* sb = Sxx + (size_t)k * DD * DD;
    for (int i = tid; i < DD * DD; i += 256) {
        int d = i >> 7, e = i & 127;
        // covar_total = Sxx - mu*S1^T - S1*mu^T + w*mu*mu^T  (exact)
        float ct = sb[i] - mu_s[d] * emp_s[e] - emp_s[d] * mu_s[e]
                 + w * mu_s[d] * mu_s[e];
        float v = ct * inv;
        if (d == e) { float t = v - 1.f; ds += t * t; }
        else        { os += v * v; }
    }
    if (tid < DD) {
        float t = mu_s[tid] - centers[k * DD + tid];
        mm = t * t;
    }

    #pragma unroll
    for (int off = 32; off > 0; off >>= 1) {
        ds += __shfl_down(ds, off);
        os += __shfl_down(os, off);
        mm += __shfl_down(mm, off);
    }
    __shared__ float rds[4], ros[4], rmm[4];
    int wv = tid >> 6, ln = tid & 63;
    if (ln == 0) { rds[wv] = ds; ros[wv] = os; rmm[wv] = mm; }
    __syncthreads();
    if (tid == 0) {
        float DS = rds[0] + rds[1] + rds[2] + rds[3];
        float OS = ros[0] + ros[1] + ros[2] + ros[3];
        float MM = rmm[0] + rmm[1] + rmm[2] + rmm[3];
        const float bd = (float)BB * (float)DD;
        float meanc = w * MM / bd;
        float covc  = w * DS / bd + w * OS / (bd * (float)(DD - 1));
        atomicAdd(&outscalars[0], meanc);
        atomicAdd(&outscalars[1], covc);
    }
}

// ---------------------------------------------------------------------------
extern "C" void kernel_launch(void* const* d_in, const int* in_sizes, int n_in,
                              void* d_out, int out_size, void* d_ws, size_t ws_size,
                              hipStream_t stream) {
    const float* x = (const float*)d_in[0];
    const float* centers = (const float*)d_in[1];
    float* out = (float*)d_out;

    char* ws = (char*)d_ws;
    float* Sxx     = (float*)ws;                            // 4 MB (zeroed)
    float* emp     = (float*)(ws + 4194304);                // 32 KB (zeroed)
    float* cw      = (float*)(ws + 4194304 + 32768);        // 256 B
    int*   sorted  = (int*)  (ws + 4194304 + 32768 + 256);  // 64 KB
    int4*  items   = (int4*) (ws + 4194304 + 32768 + 256 + 65536);       // 2 KB
    int*   itemcnt = (int*)  (ws + 4194304 + 32768 + 256 + 65536 + 2048);
    int*   assign  = (int*)  (ws + 4194304 + 32768 + 256 + 65536 + 2048 + 256); // 64 KB

    hipMemsetAsync(ws, 0, 4194304 + 32768, stream);             // Sxx + emp
    hipMemsetAsync(out + (size_t)BB * KK, 0, 2 * sizeof(float), stream);

    k_rows <<<1024, 256,  0, stream>>>(x, centers, out, assign);
    k_sort <<<1,    1024, 0, stream>>>(assign, sorted, cw, items, itemcnt);
    k_seg  <<<MAXITEMS, 256, 0, stream>>>(x, sorted, items, itemcnt, Sxx, emp);
    k_final<<<KK,   256,  0, stream>>>(Sxx, emp, cw, centers, out + (size_t)BB * KK);
}

// Round 3
// 174.181 us; speedup vs baseline: 2.5376x; 1.1128x over previous
//
#include <hip/hip_runtime.h>

#define BB 16384
#define KK 64
#define DD 128
#define SEG 256          // rows per covariance work-item
#define MAXITEMS 128     // sum_k ceil(cnt_k/SEG) <= BB/SEG + KK = 64+64

// ---------------------------------------------------------------------------
// K1: tiled GEMM formulation. Block = 64 rows x 64 clusters, K=128.
// dist = |x|^2 - 2 x.c + |c|^2 ; |x|^2 cancels in softmax AND argmin, so we
// work with e'[k] = x.c_k - 0.5|c_k|^2 (argmax e' == argmin dist).
// ---------------------------------------------------------------------------
__global__ __launch_bounds__(256) void k_rows(
    const float* __restrict__ x, const float* __restrict__ centers,
    float* __restrict__ log_resp, int* __restrict__ assign)
{
    __shared__ float xs[64][132];    // X tile, +4 pad (16B-aligned rows)
    __shared__ float ct[DD][66];     // centers transposed [d][k], pad 66
    __shared__ float cn2[KK];

    const int tid = threadIdx.x;
    const int row0 = blockIdx.x * 64;

    for (int g = tid; g < 64 * 32; g += 256) {        // X: coalesced float4
        int r = g >> 5, c4 = g & 31;
        float4 v = ((const float4*)(x + (size_t)(row0 + r) * DD))[c4];
        *(float4*)&xs[r][c4 * 4] = v;
    }
    for (int g = tid; g < KK * 32; g += 256) {        // C: transpose into LDS
        int k = g >> 5, c4 = g & 31;
        float4 v = ((const float4*)(centers + (size_t)k * DD))[c4];
        ct[c4 * 4 + 0][k] = v.x;
        ct[c4 * 4 + 1][k] = v.y;
        ct[c4 * 4 + 2][k] = v.z;
        ct[c4 * 4 + 3][k] = v.w;
    }
    __syncthreads();
    if (tid < KK) {
        float s = 0.f;
        for (int d = 0; d < DD; ++d) { float c = ct[d][tid]; s = fmaf(c, c, s); }
        cn2[tid] = s;
    }
    __syncthreads();

    const int tr = tid >> 5;          // rows tr*8 .. tr*8+7
    const int tc = tid & 31;          // clusters 2tc, 2tc+1
    const int k0 = tc * 2, k1 = k0 + 1;

    float acc0[8], acc1[8];
    #pragma unroll
    for (int i = 0; i < 8; ++i) { acc0[i] = 0.f; acc1[i] = 0.f; }

    for (int d = 0; d < DD; d += 4) {
        float2 b0 = *(const float2*)&ct[d + 0][k0];   // (k0,k1) pair, b64
        float2 b1 = *(const float2*)&ct[d + 1][k0];
        float2 b2 = *(const float2*)&ct[d + 2][k0];
        float2 b3 = *(const float2*)&ct[d + 3][k0];
        #pragma unroll
        for (int i = 0; i < 8; ++i) {
            float4 a = *(const float4*)&xs[tr * 8 + i][d];
            acc0[i] = fmaf(a.x, b0.x, acc0[i]);
            acc1[i] = fmaf(a.x, b0.y, acc1[i]);
            acc0[i] = fmaf(a.y, b1.x, acc0[i]);
            acc1[i] = fmaf(a.y, b1.y, acc1[i]);
            acc0[i] = fmaf(a.z, b2.x, acc0[i]);
            acc1[i] = fmaf(a.z, b2.y, acc1[i]);
            acc0[i] = fmaf(a.w, b3.x, acc0[i]);
            acc1[i] = fmaf(a.w, b3.y, acc1[i]);
        }
    }

    const float cn0 = 0.5f * cn2[k0], cn1 = 0.5f * cn2[k1];
    #pragma unroll
    for (int i = 0; i < 8; ++i) {
        int row = row0 + tr * 8 + i;
        float v0 = acc0[i] - cn0;
        float v1 = acc1[i] - cn1;
        float m; int idx;
        if (v1 > v0) { m = v1; idx = k1; } else { m = v0; idx = k0; }
        #pragma unroll
        for (int off = 1; off < 32; off <<= 1) {       // stays in 32-lane half
            float ov = __shfl_xor(m, off);
            int   oi = __shfl_xor(idx, off);
            if (ov > m || (ov == m && oi < idx)) { m = ov; idx = oi; }
        }
        float s = expf(v0 - m) + expf(v1 - m);
        #pragma unroll
        for (int off = 1; off < 32; off <<= 1) s += __shfl_xor(s, off);
        float ls = logf(s);
        float lr0 = fmaxf(v0 - m - ls, -18.4206807f);  // log(1e-8)
        float lr1 = fmaxf(v1 - m - ls, -18.4206807f);
        *(float2*)&log_resp[(size_t)row * KK + k0] = make_float2(lr0, lr1);
        if (tc == 0) assign[row] = idx;
    }
}

// ---------------------------------------------------------------------------
// K2 (1 block, 1024 threads): counting sort by cluster + work items + ranges.
// ---------------------------------------------------------------------------
__global__ __launch_bounds__(1024) void k_sort(
    const int* __restrict__ assign, int* __restrict__ sorted,
    float* __restrict__ cw, int4* __restrict__ items, int* __restrict__ item_count,
    int* __restrict__ ist, int* __restrict__ ien)
{
    __shared__ int whist[16][64];
    __shared__ int wcur[16][64];
    __shared__ int cnt_s[64];
    __shared__ int cbase_s[64];

    const int tid = threadIdx.x;
    const int w = tid >> 6;
    const int lane = tid & 63;

    whist[w][lane] = 0;
    __syncthreads();

    #pragma unroll
    for (int i = 0; i < 16; ++i) {
        int r = w * 1024 + i * 64 + lane;
        atomicAdd(&whist[w][assign[r]], 1);
    }
    __syncthreads();

    if (tid < 64) {
        int run = 0;
        #pragma unroll
        for (int ww = 0; ww < 16; ++ww) {
            int t = whist[ww][tid];
            whist[ww][tid] = run;
            run += t;
        }
        cnt_s[tid] = run;
        cw[tid] = (float)run;
    }
    __syncthreads();

    if (tid == 0) {
        int base = 0;
        for (int k = 0; k < KK; ++k) { cbase_s[k] = base; base += cnt_s[k]; }
        int ic = 0;
        for (int k = 0; k < KK; ++k) {
            ist[k] = ic;
            int c = cnt_s[k];
            for (int s = 0; s < c; s += SEG) {
                int4 it; it.x = k; it.y = cbase_s[k] + s;
                it.z = min(SEG, c - s); it.w = 0;
                items[ic++] = it;
            }
            ien[k] = ic;
        }
        *item_count = ic;
    }
    __syncthreads();

    wcur[w][lane] = cbase_s[lane] + whist[w][lane];
    __syncthreads();

    #pragma unroll
    for (int i = 0; i < 16; ++i) {
        int r = w * 1024 + i * 64 + lane;
        int a = assign[r];
        int p = atomicAdd(&wcur[w][a], 1);
        sorted[p] = r;
    }
}

// ---------------------------------------------------------------------------
// K3: 2 blocks per segment item (half = 64 output rows each).
// Sxx partial written NON-atomically to part[item]; col sums to emp_part[item].
// ---------------------------------------------------------------------------
__global__ __launch_bounds__(256) void k_seg(
    const float* __restrict__ x, const int* __restrict__ sorted,
    const int4* __restrict__ items, const int* __restrict__ item_count,
    float* __restrict__ part, float* __restrict__ emp_part)
{
    const int item = blockIdx.x >> 1;
    const int h = blockIdx.x & 1;
    if (item >= *item_count) return;
    int4 it = items[item];
    const int gstart = it.y, len = it.z;

    __shared__ int rows_s[SEG];
    __shared__ float xr_s[8][DD];

    const int tid = threadIdx.x;
    if (tid < len) rows_s[tid] = sorted[gstart + tid];

    const int jrow = tid >> 5;            // staged row this thread loads
    const int dc   = (tid & 31) * 4;      // float4 column offset
    const int rowoff = h * 64 + jrow * 8; // output rows rowoff..rowoff+7
    const int tc = tid & 31;              // output cols tc*4..tc*4+3

    float acc[8][4];
    #pragma unroll
    for (int i = 0; i < 8; ++i)
        #pragma unroll
        for (int l = 0; l < 4; ++l) acc[i][l] = 0.f;
    float cs0 = 0.f, cs1 = 0.f, cs2 = 0.f, cs3 = 0.f;

    __syncthreads();   // rows_s ready

    for (int it0 = 0; it0 < len; it0 += 8) {
        __syncthreads();   // WAR on xr_s
        float4 xv = {0.f, 0.f, 0.f, 0.f};
        int mi = it0 + jrow;
        if (mi < len)
            xv = *(const float4*)(x + (size_t)rows_s[mi] * DD + dc);
        *(float4*)&xr_s[jrow][dc] = xv;
        cs0 += xv.x; cs1 += xv.y; cs2 += xv.z; cs3 += xv.w;
        __syncthreads();   // RAW

        #pragma unroll
        for (int j = 0; j < 8; ++j) {
            float4 a0 = *(const float4*)&xr_s[j][rowoff];
            float4 a1 = *(const float4*)&xr_s[j][rowoff + 4];
            float4 b  = *(const float4*)&xr_s[j][tc * 4];
            float av[8] = {a0.x, a0.y, a0.z, a0.w, a1.x, a1.y, a1.z, a1.w};
            float bv[4] = {b.x, b.y, b.z, b.w};
            #pragma unroll
            for (int i = 0; i < 8; ++i)
                #pragma unroll
                for (int l = 0; l < 4; ++l)
                    acc[i][l] = fmaf(av[i], bv[l], acc[i][l]);
        }
    }

    float* pb = part + (size_t)item * (DD * DD);
    #pragma unroll
    for (int i = 0; i < 8; ++i)
        *(float4*)&pb[(rowoff + i) * DD + tc * 4] = *(float4*)&acc[i][0];

    // column sums: reduce the 8 jrow-group partials via LDS (h==0 writes)
    __syncthreads();   // WAR vs compute reads of xr_s
    xr_s[jrow][dc + 0] = cs0; xr_s[jrow][dc + 1] = cs1;
    xr_s[jrow][dc + 2] = cs2; xr_s[jrow][dc + 3] = cs3;
    __syncthreads();
    if (h == 0 && tid < 32) {
        float4 t = {0.f, 0.f, 0.f, 0.f};
        #pragma unroll
        for (int j = 0; j < 8; ++j) {
            float4 v = *(const float4*)&xr_s[j][tid * 4];
            t.x += v.x; t.y += v.y; t.z += v.z; t.w += v.w;
        }
        *(float4*)&emp_part[item * DD + tid * 4] = t;
    }
}

// ---------------------------------------------------------------------------
// K4 (fused reduce+final): 8 blocks per cluster; sum partials per element,
// centered covariance ct = Sxx - mu e^T - e mu^T + w mu mu^T, accumulate
// diag/off squared errors + mean MSE -> 2 scalar outputs.
// ---------------------------------------------------------------------------
__global__ __launch_bounds__(256) void k_final(
    const float* __restrict__ part, const float* __restrict__ emp_part,
    const float* __restrict__ cw, const float* __restrict__ centers,
    const int* __restrict__ ist, const int* __restrict__ ien,
    float* __restrict__ outscalars)
{
    const int k = blockIdx.x >> 3;
    const int p = blockIdx.x & 7;
    const int i0 = ist[k], i1 = ien[k];
    const int tid = threadIdx.x;
    const float w = cw[k];
    const float inv = 1.0f / (w + 1e-7f);

    __shared__ float mu_s[DD], emp_s[DD];
    if (tid < DD) {
        float e = 0.f;
        for (int it = i0; it < i1; ++it) e += emp_part[it * DD + tid];
        emp_s[tid] = e;
        mu_s[tid] = e * inv;
    }
    __syncthreads();

    float ds = 0.f, os = 0.f, mm = 0.f;
    const int base = p * 2048;
    #pragma unroll
    for (int q = 0; q < 8; ++q) {
        int i = base + q * 256 + tid;
        float sx = 0.f;
        for (int it = i0; it < i1; ++it)
            sx += part[(size_t)it * (DD * DD) + i];
        int d = i >> 7, e = i & 127;
        float ctv = sx - mu_s[d] * emp_s[e] - emp_s[d] * mu_s[e]
                  + w * mu_s[d] * mu_s[e];
        float v = ctv * inv;
        if (d == e) { float t = v - 1.f; ds += t * t; }
        else        { os += v * v; }
    }
    if (p == 0 && tid < DD) {
        float t = mu_s[tid] - centers[k * DD + tid];
        mm = t * t;
    }

    #pragma unroll
    for (int off = 32; off > 0; off >>= 1) {
        ds += __shfl_down(ds, off);
        os += __shfl_down(os, off);
        mm += __shfl_down(mm, off);
    }
    __shared__ float rds[4], ros[4], rmm[4];
    int wv = tid >> 6, ln = tid & 63;
    if (ln == 0) { rds[wv] = ds; ros[wv] = os; rmm[wv] = mm; }
    __syncthreads();
    if (tid == 0) {
        float DS = rds[0] + rds[1] + rds[2] + rds[3];
        float OS = ros[0] + ros[1] + ros[2] + ros[3];
        float MM = rmm[0] + rmm[1] + rmm[2] + rmm[3];
        const float bd = (float)BB * (float)DD;
        atomicAdd(&outscalars[0], w * MM / bd);
        atomicAdd(&outscalars[1], w * DS / bd + w * OS / (bd * (float)(DD - 1)));
    }
}

// ---------------------------------------------------------------------------
extern "C" void kernel_launch(void* const* d_in, const int* in_sizes, int n_in,
                              void* d_out, int out_size, void* d_ws, size_t ws_size,
                              hipStream_t stream) {
    const float* x = (const float*)d_in[0];
    const float* centers = (const float*)d_in[1];
    float* out = (float*)d_out;

    char* ws = (char*)d_ws;
    size_t off = 0;
    float* part     = (float*)(ws + off); off += (size_t)MAXITEMS * DD * DD * 4; // 8 MB
    float* emp_part = (float*)(ws + off); off += (size_t)MAXITEMS * DD * 4;      // 64 KB
    int*   sorted   = (int*)  (ws + off); off += BB * 4;                          // 64 KB
    int*   assign   = (int*)  (ws + off); off += BB * 4;                          // 64 KB
    int4*  items    = (int4*) (ws + off); off += MAXITEMS * 16;                   // 2 KB
    float* cw       = (float*)(ws + off); off += 256;
    int*   itemcnt  = (int*)  (ws + off); off += 256;
    int*   ist      = (int*)  (ws + off); off += 256;
    int*   ien      = (int*)  (ws + off); off += 256;

    hipMemsetAsync(out + (size_t)BB * KK, 0, 2 * sizeof(float), stream);

    k_rows <<<256, 256,  0, stream>>>(x, centers, out, assign);
    k_sort <<<1,   1024, 0, stream>>>(assign, sorted, cw, items, itemcnt, ist, ien);
    k_seg  <<<2 * MAXITEMS, 256, 0, stream>>>(x, sorted, items, itemcnt, part, emp_part);
    k_final<<<KK * 8, 256, 0, stream>>>(part, emp_part, cw, centers, ist, ien,
                                        out + (size_t)BB * KK);
}

// Round 4
// 162.976 us; speedup vs baseline: 2.7121x; 1.0688x over previous
//
#include <hip/hip_runtime.h>

#define BB 16384
#define KK 64
#define DD 128
#define SEG 256          // rows per covariance work-item
#define MAXITEMS 128     // sum_k ceil(cnt_k/SEG) <= BB/SEG + KK = 64+64

// ---------------------------------------------------------------------------
// K1: tiled GEMM formulation. Block = 64 rows x 64 clusters, K=128.
// dist = |x|^2 - 2 x.c + |c|^2 ; |x|^2 cancels in softmax AND argmin, so we
// work with e'[k] = x.c_k - 0.5|c_k|^2 (argmax e' == argmin dist).
// Block 0 also zeroes the two scalar outputs (consumed 3 dispatches later).
// ---------------------------------------------------------------------------
__global__ __launch_bounds__(256) void k_rows(
    const float* __restrict__ x, const float* __restrict__ centers,
    float* __restrict__ log_resp, int* __restrict__ assign,
    float* __restrict__ outscalars)
{
    __shared__ float xs[64][132];    // X tile, +4 pad (16B-aligned rows)
    __shared__ float ct[DD][66];     // centers transposed [d][k], pad 66
    __shared__ float cn2[KK];

    const int tid = threadIdx.x;
    const int row0 = blockIdx.x * 64;

    if (blockIdx.x == 0 && tid < 2) outscalars[tid] = 0.f;

    for (int g = tid; g < 64 * 32; g += 256) {        // X: coalesced float4
        int r = g >> 5, c4 = g & 31;
        float4 v = ((const float4*)(x + (size_t)(row0 + r) * DD))[c4];
        *(float4*)&xs[r][c4 * 4] = v;
    }
    for (int g = tid; g < KK * 32; g += 256) {        // C: transpose into LDS
        int k = g >> 5, c4 = g & 31;
        float4 v = ((const float4*)(centers + (size_t)k * DD))[c4];
        ct[c4 * 4 + 0][k] = v.x;
        ct[c4 * 4 + 1][k] = v.y;
        ct[c4 * 4 + 2][k] = v.z;
        ct[c4 * 4 + 3][k] = v.w;
    }
    __syncthreads();
    if (tid < KK) {
        float s = 0.f;
        for (int d = 0; d < DD; ++d) { float c = ct[d][tid]; s = fmaf(c, c, s); }
        cn2[tid] = s;
    }
    __syncthreads();

    const int tr = tid >> 5;          // rows tr*8 .. tr*8+7
    const int tc = tid & 31;          // clusters 2tc, 2tc+1
    const int k0 = tc * 2, k1 = k0 + 1;

    float acc0[8], acc1[8];
    #pragma unroll
    for (int i = 0; i < 8; ++i) { acc0[i] = 0.f; acc1[i] = 0.f; }

    for (int d = 0; d < DD; d += 4) {
        float2 b0 = *(const float2*)&ct[d + 0][k0];
        float2 b1 = *(const float2*)&ct[d + 1][k0];
        float2 b2 = *(const float2*)&ct[d + 2][k0];
        float2 b3 = *(const float2*)&ct[d + 3][k0];
        #pragma unroll
        for (int i = 0; i < 8; ++i) {
            float4 a = *(const float4*)&xs[tr * 8 + i][d];
            acc0[i] = fmaf(a.x, b0.x, acc0[i]);
            acc1[i] = fmaf(a.x, b0.y, acc1[i]);
            acc0[i] = fmaf(a.y, b1.x, acc0[i]);
            acc1[i] = fmaf(a.y, b1.y, acc1[i]);
            acc0[i] = fmaf(a.z, b2.x, acc0[i]);
            acc1[i] = fmaf(a.z, b2.y, acc1[i]);
            acc0[i] = fmaf(a.w, b3.x, acc0[i]);
            acc1[i] = fmaf(a.w, b3.y, acc1[i]);
        }
    }

    const float cn0 = 0.5f * cn2[k0], cn1 = 0.5f * cn2[k1];
    #pragma unroll
    for (int i = 0; i < 8; ++i) {
        int row = row0 + tr * 8 + i;
        float v0 = acc0[i] - cn0;
        float v1 = acc1[i] - cn1;
        float m; int idx;
        if (v1 > v0) { m = v1; idx = k1; } else { m = v0; idx = k0; }
        #pragma unroll
        for (int off = 1; off < 32; off <<= 1) {       // stays in 32-lane half
            float ov = __shfl_xor(m, off);
            int   oi = __shfl_xor(idx, off);
            if (ov > m || (ov == m && oi < idx)) { m = ov; idx = oi; }
        }
        float s = expf(v0 - m) + expf(v1 - m);
        #pragma unroll
        for (int off = 1; off < 32; off <<= 1) s += __shfl_xor(s, off);
        float ls = logf(s);
        float lr0 = fmaxf(v0 - m - ls, -18.4206807f);  // log(1e-8)
        float lr1 = fmaxf(v1 - m - ls, -18.4206807f);
        *(float2*)&log_resp[(size_t)row * KK + k0] = make_float2(lr0, lr1);
        if (tc == 0) assign[row] = idx;
    }
}

// ---------------------------------------------------------------------------
// K2 (1 block, 1024 threads): counting sort by cluster + work items + ranges.
// ---------------------------------------------------------------------------
__global__ __launch_bounds__(1024) void k_sort(
    const int* __restrict__ assign, int* __restrict__ sorted,
    float* __restrict__ cw, int4* __restrict__ items, int* __restrict__ item_count,
    int* __restrict__ ist, int* __restrict__ ien)
{
    __shared__ int whist[16][64];
    __shared__ int wcur[16][64];
    __shared__ int cnt_s[64];
    __shared__ int cbase_s[64];

    const int tid = threadIdx.x;
    const int w = tid >> 6;
    const int lane = tid & 63;

    whist[w][lane] = 0;
    __syncthreads();

    #pragma unroll
    for (int i = 0; i < 16; ++i) {
        int r = w * 1024 + i * 64 + lane;
        atomicAdd(&whist[w][assign[r]], 1);
    }
    __syncthreads();

    if (tid < 64) {
        int run = 0;
        #pragma unroll
        for (int ww = 0; ww < 16; ++ww) {
            int t = whist[ww][tid];
            whist[ww][tid] = run;
            run += t;
        }
        cnt_s[tid] = run;
        cw[tid] = (float)run;
    }
    __syncthreads();

    if (tid == 0) {
        int base = 0;
        for (int k = 0; k < KK; ++k) { cbase_s[k] = base; base += cnt_s[k]; }
        int ic = 0;
        for (int k = 0; k < KK; ++k) {
            ist[k] = ic;
            int c = cnt_s[k];
            for (int s = 0; s < c; s += SEG) {
                int4 it; it.x = k; it.y = cbase_s[k] + s;
                it.z = min(SEG, c - s); it.w = 0;
                items[ic++] = it;
            }
            ien[k] = ic;
        }
        *item_count = ic;
    }
    __syncthreads();

    wcur[w][lane] = cbase_s[lane] + whist[w][lane];
    __syncthreads();

    #pragma unroll
    for (int i = 0; i < 16; ++i) {
        int r = w * 1024 + i * 64 + lane;
        int a = assign[r];
        int p = atomicAdd(&wcur[w][a], 1);
        sorted[p] = r;
    }
}

// ---------------------------------------------------------------------------
// K3: 2 blocks per segment item (half = 64 output rows each).
// Sxx partial written NON-atomically to part[item]; col sums to emp_part[item].
// ---------------------------------------------------------------------------
__global__ __launch_bounds__(256) void k_seg(
    const float* __restrict__ x, const int* __restrict__ sorted,
    const int4* __restrict__ items, const int* __restrict__ item_count,
    float* __restrict__ part, float* __restrict__ emp_part)
{
    const int item = blockIdx.x >> 1;
    const int h = blockIdx.x & 1;
    if (item >= *item_count) return;
    int4 it = items[item];
    const int gstart = it.y, len = it.z;

    __shared__ int rows_s[SEG];
    __shared__ float xr_s[8][DD];

    const int tid = threadIdx.x;
    if (tid < len) rows_s[tid] = sorted[gstart + tid];

    const int jrow = tid >> 5;            // staged row this thread loads
    const int dc   = (tid & 31) * 4;      // float4 column offset
    const int rowoff = h * 64 + jrow * 8; // output rows rowoff..rowoff+7
    const int tc = tid & 31;              // output cols tc*4..tc*4+3

    float acc[8][4];
    #pragma unroll
    for (int i = 0; i < 8; ++i)
        #pragma unroll
        for (int l = 0; l < 4; ++l) acc[i][l] = 0.f;
    float cs0 = 0.f, cs1 = 0.f, cs2 = 0.f, cs3 = 0.f;

    __syncthreads();   // rows_s ready

    for (int it0 = 0; it0 < len; it0 += 8) {
        __syncthreads();   // WAR on xr_s
        float4 xv = {0.f, 0.f, 0.f, 0.f};
        int mi = it0 + jrow;
        if (mi < len)
            xv = *(const float4*)(x + (size_t)rows_s[mi] * DD + dc);
        *(float4*)&xr_s[jrow][dc] = xv;
        cs0 += xv.x; cs1 += xv.y; cs2 += xv.z; cs3 += xv.w;
        __syncthreads();   // RAW

        #pragma unroll
        for (int j = 0; j < 8; ++j) {
            float4 a0 = *(const float4*)&xr_s[j][rowoff];
            float4 a1 = *(const float4*)&xr_s[j][rowoff + 4];
            float4 b  = *(const float4*)&xr_s[j][tc * 4];
            float av[8] = {a0.x, a0.y, a0.z, a0.w, a1.x, a1.y, a1.z, a1.w};
            float bv[4] = {b.x, b.y, b.z, b.w};
            #pragma unroll
            for (int i = 0; i < 8; ++i)
                #pragma unroll
                for (int l = 0; l < 4; ++l)
                    acc[i][l] = fmaf(av[i], bv[l], acc[i][l]);
        }
    }

    float* pb = part + (size_t)item * (DD * DD);
    #pragma unroll
    for (int i = 0; i < 8; ++i)
        *(float4*)&pb[(rowoff + i) * DD + tc * 4] = *(float4*)&acc[i][0];

    // column sums: reduce the 8 jrow-group partials via LDS (h==0 writes)
    __syncthreads();   // WAR vs compute reads of xr_s
    xr_s[jrow][dc + 0] = cs0; xr_s[jrow][dc + 1] = cs1;
    xr_s[jrow][dc + 2] = cs2; xr_s[jrow][dc + 3] = cs3;
    __syncthreads();
    if (h == 0 && tid < 32) {
        float4 t = {0.f, 0.f, 0.f, 0.f};
        #pragma unroll
        for (int j = 0; j < 8; ++j) {
            float4 v = *(const float4*)&xr_s[j][tid * 4];
            t.x += v.x; t.y += v.y; t.z += v.z; t.w += v.w;
        }
        *(float4*)&emp_part[item * DD + tid * 4] = t;
    }
}

// ---------------------------------------------------------------------------
// K4 (fused reduce+final): 16 blocks per cluster, each owns a 1024-element
// slab. Sum partials (float4, independent addresses -> MLP), form centered
// covariance inline, accumulate diag/off errors + mean MSE into 2 scalars.
// ---------------------------------------------------------------------------
__global__ __launch_bounds__(256) void k_redfinal(
    const float* __restrict__ part, const float* __restrict__ emp_part,
    const float* __restrict__ cw, const float* __restrict__ centers,
    const int* __restrict__ ist, const int* __restrict__ ien,
    float* __restrict__ outscalars)
{
    const int k = blockIdx.x >> 4;
    const int p = blockIdx.x & 15;
    const int i0 = ist[k], i1 = ien[k];
    const int tid = threadIdx.x;
    const float w = cw[k];
    const float inv = 1.0f / (w + 1e-7f);

    __shared__ float mu_s[DD], emp_s[DD];
    if (tid < DD) {
        float e = 0.f;
        for (int it = i0; it < i1; ++it) e += emp_part[it * DD + tid];
        emp_s[tid] = e;
        mu_s[tid] = e * inv;
    }
    __syncthreads();

    const int i = p * 1024 + tid * 4;     // 4 consecutive elems, same row d
    float4 sx = {0.f, 0.f, 0.f, 0.f};
    for (int it = i0; it < i1; ++it) {
        float4 v = *(const float4*)&part[(size_t)it * (DD * DD) + i];
        sx.x += v.x; sx.y += v.y; sx.z += v.z; sx.w += v.w;
    }

    const int d = i >> 7;
    const int e0 = i & 127;
    const float md = mu_s[d], ed = emp_s[d];
    float sv[4] = {sx.x, sx.y, sx.z, sx.w};
    float ds = 0.f, os = 0.f, mm = 0.f;
    #pragma unroll
    for (int l = 0; l < 4; ++l) {
        int e = e0 + l;
        float ctv = sv[l] - md * emp_s[e] - ed * mu_s[e] + w * md * mu_s[e];
        float v = ctv * inv;
        if (e == d) { float t = v - 1.f; ds += t * t; }
        else        { os += v * v; }
    }
    if (p == 0 && tid < DD) {
        float t = mu_s[tid] - centers[k * DD + tid];
        mm = t * t;
    }

    #pragma unroll
    for (int off = 32; off > 0; off >>= 1) {
        ds += __shfl_down(ds, off);
        os += __shfl_down(os, off);
        mm += __shfl_down(mm, off);
    }
    __shared__ float rds[4], ros[4], rmm[4];
    int wv = tid >> 6, ln = tid & 63;
    if (ln == 0) { rds[wv] = ds; ros[wv] = os; rmm[wv] = mm; }
    __syncthreads();
    if (tid == 0) {
        float DS = rds[0] + rds[1] + rds[2] + rds[3];
        float OS = ros[0] + ros[1] + ros[2] + ros[3];
        float MM = rmm[0] + rmm[1] + rmm[2] + rmm[3];
        const float bd = (float)BB * (float)DD;
        atomicAdd(&outscalars[0], w * MM / bd);
        atomicAdd(&outscalars[1], w * DS / bd + w * OS / (bd * (float)(DD - 1)));
    }
}

// ---------------------------------------------------------------------------
extern "C" void kernel_launch(void* const* d_in, const int* in_sizes, int n_in,
                              void* d_out, int out_size, void* d_ws, size_t ws_size,
                              hipStream_t stream) {
    const float* x = (const float*)d_in[0];
    const float* centers = (const float*)d_in[1];
    float* out = (float*)d_out;
    float* outscalars = out + (size_t)BB * KK;

    char* ws = (char*)d_ws;
    size_t off = 0;
    float* part     = (float*)(ws + off); off += (size_t)MAXITEMS * DD * DD * 4; // 8 MB
    float* emp_part = (float*)(ws + off); off += (size_t)MAXITEMS * DD * 4;      // 64 KB
    int*   sorted   = (int*)  (ws + off); off += BB * 4;                          // 64 KB
    int*   assign   = (int*)  (ws + off); off += BB * 4;                          // 64 KB
    int4*  items    = (int4*) (ws + off); off += MAXITEMS * 16;                   // 2 KB
    float* cw       = (float*)(ws + off); off += 256;
    int*   itemcnt  = (int*)  (ws + off); off += 256;
    int*   ist      = (int*)  (ws + off); off += 256;
    int*   ien      = (int*)  (ws + off); off += 256;

    k_rows    <<<256, 256,  0, stream>>>(x, centers, out, assign, outscalars);
    k_sort    <<<1,   1024, 0, stream>>>(assign, sorted, cw, items, itemcnt, ist, ien);
    k_seg     <<<2 * MAXITEMS, 256, 0, stream>>>(x, sorted, items, itemcnt, part, emp_part);
    k_redfinal<<<KK * 16, 256, 0, stream>>>(part, emp_part, cw, centers, ist, ien,
                                            outscalars);
}